// Round 7
// baseline (332.303 us; speedup 1.0000x reference)
//
#include <hip/hip_runtime.h>

// ReActNet BasicBlock forward: out = BN(binary_conv3x3(sign(x), scale*sign(w))) + x
//
// i8 MFMA implicit-GEMM — round-1-proven structure + register prefetch:
//   EXACT round-1 geometry/layout (grid 3136, 2 chains/wave, otile=oh*2+wo,
//   linear padded NHWC S, separate border kernel, r1 workspace order) —
//   the only delta is the bconv inner loop: double-buffered register
//   prefetch of tap t+1 (8 B-frags + 4 A-frags) issued before tap t's
//   MFMA burst, and launch_bounds(256,3) for register headroom.
//   (Rounds 4-6's restructured geometry failed identically; reverted.)

#define N_   64
#define C_   128
#define H_   56
#define W_   56
#define HW_  (H_*W_)       // 3136
#define PH_  (H_+2)        // 58
#define PW_  (W_+2)        // 58
#define PHW_ (PH_*PW_)     // 3364
#define NPIX (N_*HW_)      // 200704

typedef int v4i  __attribute__((ext_vector_type(4)));
typedef int v16i __attribute__((ext_vector_type(16)));

__device__ __forceinline__ unsigned sign_byte(unsigned u) {
    // {+1, 0 (exact zero incl -0.0), 0xFF}
    return ((u << 1) == 0u) ? 0u : ((u >> 31) ? 0xFFu : 1u);
}

// ---------------------------------------------------------------------------
// Kernel 1a: per-channel scale + BN fold. One wave per output channel.
//   (round-1-verified, unchanged)
// ---------------------------------------------------------------------------
__global__ void prep_ab_kernel(const float* __restrict__ w,
                               const float* __restrict__ gamma,
                               const float* __restrict__ beta,
                               const float* __restrict__ bn_mean,
                               const float* __restrict__ bn_var,
                               float2* __restrict__ AB) {
    const int o = blockIdx.x;
    const int lane = threadIdx.x;          // 0..63
    const float* wo = w + o * 1152;

    float s = 0.f;
    #pragma unroll
    for (int k = 0; k < 18; k++) s += fabsf(wo[k * 64 + lane]);
    #pragma unroll
    for (int off = 32; off > 0; off >>= 1) s += __shfl_down(s, off);
    if (lane == 0) {
        float scale = s * (1.0f / 1152.0f);
        float inv = gamma[o] * rsqrtf(bn_var[o] + 1e-5f);
        float2 ab; ab.x = scale * inv; ab.y = beta[o] - bn_mean[o] * inv;
        AB[o] = ab;
    }
}

// ---------------------------------------------------------------------------
// Kernel 1b: weight signs in MFMA A-fragment layout (round-1-verified).
//   A-frag (32x32x32 i8): lane l holds A[m = l&31][k = (l>>5)*16 + j], j=0..15
//   wfrag[((otile*9 + tap)*4 + ks)*64 + lane] : v4i
// ---------------------------------------------------------------------------
__global__ void prep_wfrag_kernel(const float* __restrict__ w,
                                  v4i* __restrict__ wfrag) {
    const int b = blockIdx.x;              // 0..35 = otile*9 + tap
    const int otile = b / 9, tap = b - 9 * otile;
    const int tid = threadIdx.x;
    const int ks = tid >> 6, lane = tid & 63;
    const int o = otile * 32 + (lane & 31);
    const int cbase = ks * 32 + (lane >> 5) * 16;
    const float* wp = w + o * 1152 + cbase * 9 + tap;   // w[o][c][tap], stride 9

    unsigned d[4];
    #pragma unroll
    for (int i = 0; i < 4; i++) {
        unsigned wd = 0;
        #pragma unroll
        for (int j = 0; j < 4; j++) {
            unsigned u = __float_as_uint(wp[(i * 4 + j) * 9]);
            wd |= sign_byte(u) << (8 * j);
        }
        d[i] = wd;
    }
    v4i t; t.x = (int)d[0]; t.y = (int)d[1]; t.z = (int)d[2]; t.w = (int)d[3];
    wfrag[((otile * 9 + tap) * 4 + ks) * 64 + lane] = t;
}

// ---------------------------------------------------------------------------
// Kernel 2: binarize x into padded LINEAR NHWC i8 (round-1-verified).
// ---------------------------------------------------------------------------
__global__ __launch_bounds__(256) void pack_s_kernel(
        const float* __restrict__ x, char* __restrict__ S) {
    const int tid = threadIdx.x;
    const int pixl = tid & 63, q = tid >> 6;      // q = channel quarter
    const int g = blockIdx.x * 64 + pixl;          // 0..NPIX-1
    const int n = g / HW_;
    const int p = g - n * HW_;
    const int row = p / W_, col = p - row * W_;

    const float* xp = x + ((size_t)n * C_ + q * 32) * HW_ + p;
    unsigned w[8];
    #pragma unroll
    for (int i = 0; i < 8; i++) {
        unsigned wd = 0;
        #pragma unroll
        for (int j = 0; j < 4; j++) {
            unsigned u = __float_as_uint(xp[(i * 4 + j) * HW_]);
            wd |= sign_byte(u) << (8 * j);
        }
        w[i] = wd;
    }
    char* dst = S + (size_t)((n * PH_ + row + 1) * PW_ + col + 1) * 128 + q * 32;
    v4i t0; t0.x=(int)w[0]; t0.y=(int)w[1]; t0.z=(int)w[2]; t0.w=(int)w[3];
    v4i t1; t1.x=(int)w[4]; t1.y=(int)w[5]; t1.z=(int)w[6]; t1.w=(int)w[7];
    ((v4i*)dst)[0] = t0;
    ((v4i*)dst)[1] = t1;
}

// ---------------------------------------------------------------------------
// Kernel 2b: zero the padded border pixels (128 B each). (round-1-verified)
// ---------------------------------------------------------------------------
__global__ void border_s_kernel(char* __restrict__ S) {
    int bt = blockIdx.x * 256 + threadIdx.x;
    if (bt >= N_ * 228) return;                 // 2*58 + 2*56 = 228 per image
    int n = bt / 228, e = bt - n * 228;
    int ph, pw;
    if (e < 58)       { ph = 0;  pw = e; }
    else if (e < 116) { ph = 57; pw = e - 58; }
    else { int i = e - 116; ph = 1 + (i >> 1); pw = (i & 1) ? 57 : 0; }
    v4i z = {};
    v4i* dst = (v4i*)(S + (size_t)((n * PH_ + ph) * PW_ + pw) * 128);
    #pragma unroll
    for (int i = 0; i < 8; i++) dst[i] = z;
}

// ---------------------------------------------------------------------------
// Kernel 3: i8 MFMA conv + BN + residual — round-1 geometry, prefetched.
//   grid = (3136): bid swizzle (b0&7)*392 + b0>>3 (bijective, 3136%8==0).
//   pb = 128-pixel block (may span images; per-lane n/p handles it),
//   oh = 64-channel half; wave (wo,wp): otile = oh*2+wo, pixel half wp.
//   Inner loop: tap t+1's 12 loads issued before tap t's 8 MFMAs.
// ---------------------------------------------------------------------------
#define TOFF(t) ((((t) / 3 - 1) * PW_ + ((t) % 3 - 1)) * 128)

__global__ __launch_bounds__(256, 3) void bconv_mfma_kernel(
        const char* __restrict__ S,
        const v4i* __restrict__ wfrag,
        const float2* __restrict__ AB,
        const float* __restrict__ x,
        float* __restrict__ out) {
    const int tid = threadIdx.x;
    const int lane = tid & 63;
    const int wid = tid >> 6;                  // 0..3
    const int b0 = blockIdx.x;
    const int bid = (b0 & 7) * 392 + (b0 >> 3);
    const int pb = bid >> 1;                   // pixel-block 0..1567 (128 px)
    const int oh = bid & 1;                    // o-half
    const int wo = wid & 1, wp = wid >> 1;
    const int otile = oh * 2 + wo;             // 0..3
    const int l31 = lane & 31, lhi = lane >> 5;

    // Per-lane pixel geometry for the wave's two 32-pixel chains.
    int n0, p0, n1, p1; int sb0, sb1;
    {
        int g = (pb * 4 + wp * 2) * 32 + l31;
        n0 = g / HW_; p0 = g - n0 * HW_;
        int r = p0 / W_, c = p0 - r * W_;
        sb0 = ((n0 * PH_ + r + 1) * PW_ + c + 1) * 128 + lhi * 16;
    }
    {
        int g = (pb * 4 + wp * 2 + 1) * 32 + l31;
        n1 = g / HW_; p1 = g - n1 * HW_;
        int r = p1 / W_, c = p1 - r * W_;
        sb1 = ((n1 * PH_ + r + 1) * PW_ + c + 1) * 128 + lhi * 16;
    }

    const v4i* wf = wfrag + (size_t)otile * (9 * 4 * 64) + lane;
    const char* s0 = S + sb0;
    const char* s1 = S + sb1;

    v16i acc0 = {};
    v16i acc1 = {};

    // Prologue: tap 0 into current buffers.
    v4i Acur[4], Bc0[4], Bc1[4];
    #pragma unroll
    for (int ks = 0; ks < 4; ks++) {
        Acur[ks] = wf[ks * 64];
        Bc0[ks]  = *(const v4i*)(s0 + TOFF(0) + ks * 32);
        Bc1[ks]  = *(const v4i*)(s1 + TOFF(0) + ks * 32);
    }

    #pragma unroll
    for (int t = 0; t < 9; t++) {
        // Prefetch tap t+1 (independent loads, issued before MFMA burst).
        v4i Anxt[4], Bn0[4], Bn1[4];
        if (t < 8) {
            const int tpn = TOFF(t + 1);
            #pragma unroll
            for (int ks = 0; ks < 4; ks++) {
                Anxt[ks] = wf[(t + 1) * 256 + ks * 64];
                Bn0[ks]  = *(const v4i*)(s0 + tpn + ks * 32);
                Bn1[ks]  = *(const v4i*)(s1 + tpn + ks * 32);
            }
        }
        // Consume tap t.
        #pragma unroll
        for (int ks = 0; ks < 4; ks++) {
            acc0 = __builtin_amdgcn_mfma_i32_32x32x32_i8(Acur[ks], Bc0[ks],
                                                         acc0, 0, 0, 0);
            acc1 = __builtin_amdgcn_mfma_i32_32x32x32_i8(Acur[ks], Bc1[ks],
                                                         acc1, 0, 0, 0);
        }
        // Swap (register moves; SSA after full unroll).
        if (t < 8) {
            #pragma unroll
            for (int ks = 0; ks < 4; ks++) {
                Acur[ks] = Anxt[ks]; Bc0[ks] = Bn0[ks]; Bc1[ks] = Bn1[ks];
            }
        }
    }

    // Epilogue: out = A*dot + B + x  (round-1-verified mapping)
    const int orow = otile * 32 + 4 * lhi;
    {
        unsigned base = (unsigned)n0 * (unsigned)(C_ * HW_) + (unsigned)p0;
        #pragma unroll
        for (int r = 0; r < 16; r++) {
            int o = orow + (r & 3) + 8 * (r >> 2);
            float2 ab = AB[o];
            unsigned idx = base + (unsigned)o * (unsigned)HW_;
            out[idx] = fmaf(ab.x, (float)acc0[r], ab.y) + x[idx];
        }
    }
    {
        unsigned base = (unsigned)n1 * (unsigned)(C_ * HW_) + (unsigned)p1;
        #pragma unroll
        for (int r = 0; r < 16; r++) {
            int o = orow + (r & 3) + 8 * (r >> 2);
            float2 ab = AB[o];
            unsigned idx = base + (unsigned)o * (unsigned)HW_;
            out[idx] = fmaf(ab.x, (float)acc1[r], ab.y) + x[idx];
        }
    }
}

// ---------------------------------------------------------------------------
extern "C" void kernel_launch(void* const* d_in, const int* in_sizes, int n_in,
                              void* d_out, int out_size, void* d_ws, size_t ws_size,
                              hipStream_t stream) {
    const float* x      = (const float*)d_in[0];
    const float* weight = (const float*)d_in[1];
    const float* gamma  = (const float*)d_in[2];
    const float* beta   = (const float*)d_in[3];
    const float* bnmean = (const float*)d_in[4];
    const float* bnvar  = (const float*)d_in[5];
    float* out = (float*)d_out;

    // Round-1 workspace order (proven): wfrag, AB, S.
    char* ws = (char*)d_ws;
    v4i*    wfrag = (v4i*)ws;                       // 147456 B
    float2* AB    = (float2*)(ws + 147456);         // 1024 B
    char*   S     = ws + 148480;                    // 64*3364*128 = 27541504 B

    prep_ab_kernel<<<128, 64, 0, stream>>>(weight, gamma, beta, bnmean, bnvar, AB);
    prep_wfrag_kernel<<<36, 256, 0, stream>>>(weight, wfrag);
    pack_s_kernel<<<NPIX / 64, 256, 0, stream>>>(x, S);
    border_s_kernel<<<(N_ * 228 + 255) / 256, 256, 0, stream>>>(S);
    bconv_mfma_kernel<<<3136, 256, 0, stream>>>(S, wfrag, AB, x, out);
}

// Round 8
// 247.937 us; speedup vs baseline: 1.3403x; 1.3403x over previous
//
#include <hip/hip_runtime.h>

// ReActNet BasicBlock forward: out = BN(binary_conv3x3(sign(x), scale*sign(w))) + x
//
// i8 MFMA implicit-GEMM, LDS-staged stencil (r4 design, workspace-fixed):
//   sign(x) -> padded NHWC i8 tensor S[n][58][58][128], XOR-swizzled in 16B
//              slots (slot' = slot ^ (P&7)) so LDS ds_read_b128 is
//              bank-conflict-free after a LINEAR global_load_lds copy.
//   sign(w) -> A-fragment-layout blob wfrag[otile][tap][ks][lane] (v4i)
//   Block = 256 thr = 4 waves = 4 o-tiles (all 128 o); each wave: 32 o x
//   128 px as 4 independent MFMA chains. S window (264 px = 33 KB) staged
//   ONCE per block, serves all 9 taps x 4 o-tiles.
//   *** r4-6 bug was NOT logic: wfrag was placed at ws+27,541,504 but S is
//   27,557,888 B (215,296*128) -> pack clobbered weights. Fixed offsets. ***

#define N_   64
#define C_   128
#define H_   56
#define W_   56
#define HW_  (H_*W_)       // 3136
#define PH_  (H_+2)        // 58
#define PW_  (W_+2)        // 58
#define PHW_ (PH_*PW_)     // 3364
#define NPIX (N_*HW_)      // 200704
#define NPAD (N_*PHW_)     // 215296
#define SBYTES ((size_t)NPAD * 128)   // 27,557,888
#define SPIX 264           // staged pixels per block (33792 B LDS)

typedef int v4i  __attribute__((ext_vector_type(4)));
typedef int v16i __attribute__((ext_vector_type(16)));

__device__ __forceinline__ void glds16(const char* g, char* l) {
    __builtin_amdgcn_global_load_lds(
        (const __attribute__((address_space(1))) void*)g,
        (__attribute__((address_space(3))) void*)l, 16, 0, 0);
}

__device__ __forceinline__ unsigned sign_byte(unsigned u) {
    // {+1, 0 (exact zero incl -0.0), 0xFF}
    return ((u << 1) == 0u) ? 0u : ((u >> 31) ? 0xFFu : 1u);
}

// ---------------------------------------------------------------------------
// Kernel 1: fused weight prep. One 64-thread block per output channel o.
//   - scale = mean|w|, AB[o] = {scale*inv, beta - mean*inv}
//   - wfrag fragments: frag f = (t, ks, lh); lane slot = (lh<<5)|(o&31)
// ---------------------------------------------------------------------------
__global__ void prep_w_kernel(const float* __restrict__ w,
                              const float* __restrict__ gamma,
                              const float* __restrict__ beta,
                              const float* __restrict__ bn_mean,
                              const float* __restrict__ bn_var,
                              v4i* __restrict__ wfrag,
                              float2* __restrict__ AB) {
    const int o = blockIdx.x;
    const int lane = threadIdx.x;          // 0..63
    const float* wo = w + o * 1152;

    float s = 0.f;
    #pragma unroll
    for (int k = 0; k < 18; k++) s += fabsf(wo[k * 64 + lane]);
    #pragma unroll
    for (int off = 32; off > 0; off >>= 1) s += __shfl_down(s, off);

    // fragments: 72 total; lane builds f=lane, and f=64+lane for lane<8
    #pragma unroll
    for (int rep = 0; rep < 2; rep++) {
        int f = rep * 64 + lane;
        if (f < 72) {
            int t = f >> 3, ks = (f >> 1) & 3, lh = f & 1;
            int cbase = ks * 32 + lh * 16;
            unsigned d[4];
            #pragma unroll
            for (int i = 0; i < 4; i++) {
                unsigned wd = 0;
                #pragma unroll
                for (int j = 0; j < 4; j++) {
                    unsigned u = __float_as_uint(wo[(cbase + i * 4 + j) * 9 + t]);
                    wd |= sign_byte(u) << (8 * j);
                }
                d[i] = wd;
            }
            v4i v; v.x=(int)d[0]; v.y=(int)d[1]; v.z=(int)d[2]; v.w=(int)d[3];
            wfrag[(((o >> 5) * 9 + t) * 4 + ks) * 64 + (lh << 5) + (o & 31)] = v;
        }
    }
    if (lane == 0) {
        float scale = s * (1.0f / 1152.0f);
        float inv = gamma[o] * rsqrtf(bn_var[o] + 1e-5f);
        float2 ab; ab.x = scale * inv; ab.y = beta[o] - bn_mean[o] * inv;
        AB[o] = ab;
    }
}

// ---------------------------------------------------------------------------
// Kernel 2: binarize x into padded, slot-swizzled NHWC i8. Border blocks
//   (blockIdx >= 3136) zero the padded frame (swizzle-invariant zeros).
// ---------------------------------------------------------------------------
__global__ __launch_bounds__(256) void pack_s_kernel(
        const float* __restrict__ x, char* __restrict__ S) {
    const int tid = threadIdx.x;
    const int pixl = tid & 63, q = tid >> 6;      // q = channel quarter
    const int b = blockIdx.x;

    if (b >= NPIX / 64) {                          // border: 228 blocks
        int bt = (b - NPIX / 64) * 64 + pixl;      // 0..14591
        int n = bt / 228, e = bt - n * 228;
        int ph, pw;
        if (e < 58)       { ph = 0;  pw = e; }
        else if (e < 116) { ph = 57; pw = e - 58; }
        else { int i = e - 116; ph = 1 + (i >> 1); pw = (i & 1) ? 57 : 0; }
        v4i z = {};
        char* dst = S + (size_t)((n * PH_ + ph) * PW_ + pw) * 128 + q * 32;
        ((v4i*)dst)[0] = z;
        ((v4i*)dst)[1] = z;
        return;
    }

    const int g = b * 64 + pixl;                   // 0..NPIX-1
    const int n = g / HW_;
    const int p = g - n * HW_;
    const int row = p / W_, col = p - row * W_;

    const float* xp = x + ((size_t)n * C_ + q * 32) * HW_ + p;
    unsigned w[8];
    #pragma unroll
    for (int i = 0; i < 8; i++) {
        unsigned wd = 0;
        #pragma unroll
        for (int j = 0; j < 4; j++) {
            unsigned u = __float_as_uint(xp[(i * 4 + j) * HW_]);
            wd |= sign_byte(u) << (8 * j);
        }
        w[i] = wd;
    }
    const int P = (n * PH_ + row + 1) * PW_ + col + 1;   // padded pixel index
    const int m = P & 7;                                  // swizzle key
    char* base = S + (size_t)P * 128;
    v4i t0; t0.x=(int)w[0]; t0.y=(int)w[1]; t0.z=(int)w[2]; t0.w=(int)w[3];
    v4i t1; t1.x=(int)w[4]; t1.y=(int)w[5]; t1.z=(int)w[6]; t1.w=(int)w[7];
    *(v4i*)(base + (((2 * q)     ^ m) << 4)) = t0;
    *(v4i*)(base + (((2 * q + 1) ^ m) << 4)) = t1;
}

// ---------------------------------------------------------------------------
// Kernel 3: i8 MFMA conv + BN + residual, LDS-staged.
//   grid = 1600 = 64 images * 25 pixel-blocks (128 px; tail 64 px masked).
//   XCD-bijective swizzle (1600 % 8 == 0).
//   ds_read addr: (lp<<7) ^ ((lp&7)<<4) ^ ((2ks+lhi)<<4)  [XOR-composable;
//   qs8 8-aligned => (P-qs8)&7 == P&7, matching pack's write key]
// ---------------------------------------------------------------------------
__global__ __launch_bounds__(256, 3) void bconv_mfma_kernel(
        const char* __restrict__ S,
        const v4i* __restrict__ wfrag,
        const float2* __restrict__ AB,
        const float* __restrict__ x,
        float* __restrict__ out) {
    __shared__ char Sl[SPIX * 128];

    const int tid = threadIdx.x;
    const int lane = tid & 63;
    const int wid = tid >> 6;                  // wave = o-tile
    const int l31 = lane & 31, lhi = lane >> 5;

    const int b0 = blockIdx.x;
    const int bid = (b0 & 7) * 200 + (b0 >> 3);
    const int n = bid / 25;
    const int pb = bid - n * 25;
    const int p0 = pb * 128;

    const int r0 = p0 / W_, c0 = p0 - r0 * W_;
    const int P0 = (n * PH_ + r0 + 1) * PW_ + (c0 + 1);
    const int qs8 = (P0 - PW_ - 1) & ~7;       // 8-aligned staging start

    // Stage S[qs8 .. qs8+SPIX) -> LDS, linear copy (33 wave-issues of 1 KiB).
    // Last-image blocks over-read <=10.2 KiB past S end -> lands in wfrag
    // (mapped, read-only garbage in LDS slots that are never addressed).
    {
        const char* gsrc = S + (size_t)qs8 * 128 + lane * 16;
        #pragma unroll
        for (int i = 0; i < 9; i++) {
            int seg = i * 4 + wid;             // wave-uniform predicate
            if (seg < (SPIX * 128) / 1024)
                glds16(gsrc + seg * 1024, &Sl[seg * 1024]);
        }
    }

    // Per-chain geometry (overlaps with staging loads).
    int lpx[4]; bool val[4]; int pix[4];
    #pragma unroll
    for (int ch = 0; ch < 4; ch++) {
        int p = p0 + ch * 32 + l31;
        val[ch] = (p < HW_);
        if (!val[ch]) p = HW_ - 1;
        pix[ch] = p;
        int r = p / W_, c = p - r * W_;
        lpx[ch] = (n * PH_ + r + 1) * PW_ + (c + 1) - qs8;
    }
    const int kc1 = lhi << 4;

    __syncthreads();

    v16i acc[4] = {};
    const v4i* wbase = wfrag + (size_t)wid * (9 * 4 * 64) + lane;

    // A-fragment double-buffer (B is LDS-latency; A is the L2-latency chain).
    v4i Acur[4], Anxt[4];
    #pragma unroll
    for (int ks = 0; ks < 4; ks++) Acur[ks] = wbase[ks * 64];

    #pragma unroll
    for (int t = 0; t < 9; t++) {
        if (t < 8) {
            #pragma unroll
            for (int ks = 0; ks < 4; ks++)
                Anxt[ks] = wbase[((t + 1) * 4 + ks) * 64];
        }
        const int tp = (t / 3 - 1) * PW_ + (t % 3 - 1);
        int A0[4];
        #pragma unroll
        for (int ch = 0; ch < 4; ch++) {
            int lpt = lpx[ch] + tp;
            A0[ch] = (lpt << 7) ^ ((lpt & 7) << 4) ^ kc1;
        }
        #pragma unroll
        for (int ks = 0; ks < 4; ks++) {
            #pragma unroll
            for (int ch = 0; ch < 4; ch++) {
                v4i bb = *(const v4i*)(&Sl[A0[ch] ^ (ks << 5)]);
                acc[ch] = __builtin_amdgcn_mfma_i32_32x32x32_i8(Acur[ks], bb,
                                                                acc[ch], 0, 0, 0);
            }
        }
        if (t < 8) {
            #pragma unroll
            for (int ks = 0; ks < 4; ks++) Acur[ks] = Anxt[ks];
        }
    }

    // Epilogue: out = A*dot + B + x
    const int obase = wid * 32 + 4 * lhi;
    #pragma unroll
    for (int ch = 0; ch < 4; ch++) {
        if (!val[ch]) continue;
        unsigned base = (unsigned)n * (unsigned)(C_ * HW_) + (unsigned)pix[ch];
        #pragma unroll
        for (int r = 0; r < 16; r++) {
            int o = obase + (r & 3) + 8 * (r >> 2);
            float2 ab = AB[o];
            unsigned idx = base + (unsigned)o * (unsigned)HW_;
            out[idx] = fmaf(ab.x, (float)acc[ch][r], ab.y) + x[idx];
        }
    }
}

// ---------------------------------------------------------------------------
extern "C" void kernel_launch(void* const* d_in, const int* in_sizes, int n_in,
                              void* d_out, int out_size, void* d_ws, size_t ws_size,
                              hipStream_t stream) {
    const float* x      = (const float*)d_in[0];
    const float* weight = (const float*)d_in[1];
    const float* gamma  = (const float*)d_in[2];
    const float* beta   = (const float*)d_in[3];
    const float* bnmean = (const float*)d_in[4];
    const float* bnvar  = (const float*)d_in[5];
    float* out = (float*)d_out;

    // CORRECTED layout: S = NPAD*128 = 27,557,888 B (r4-6 used 27,541,504,
    // overlapping wfrag with S's tail -> pack clobbered weights).
    // Total = 27,706,368 B, exactly the footprint r7 proved mapped.
    char* ws = (char*)d_ws;
    char*   S     = ws;                                   // SBYTES
    v4i*    wfrag = (v4i*)(ws + SBYTES);                  // 147456 B
    float2* AB    = (float2*)(ws + SBYTES + 147456);      // 1024 B

    prep_w_kernel<<<128, 64, 0, stream>>>(weight, gamma, beta, bnmean, bnvar,
                                          wfrag, AB);
    pack_s_kernel<<<NPIX / 64 + 228, 256, 0, stream>>>(x, S);
    bconv_mfma_kernel<<<1600, 256, 0, stream>>>(S, wfrag, AB, x, out);
}